// Round 5
// baseline (321.393 us; speedup 1.0000x reference)
//
#include <hip/hip_runtime.h>
#include <hip/hip_bf16.h>

#define DIM 1024
#define HEADS 16
#define DH 64
#define SEQ 2048
#define BATCH 4
#define ROWS (BATCH * SEQ)   // 8192
#define NQKV (3 * DIM)       // 3072

typedef __attribute__((ext_vector_type(8))) __bf16 bf16x8;
typedef __attribute__((ext_vector_type(4))) __bf16 bf16x4;
typedef __attribute__((ext_vector_type(4))) float f32x4;

__device__ inline void gload16(const void* g, void* l) {
  __builtin_amdgcn_global_load_lds(
      (const __attribute__((address_space(1))) void*)g,
      (__attribute__((address_space(3))) void*)l, 16, 0, 0);
}

__device__ inline float fast_exp2(float x) {
#if __has_builtin(__builtin_amdgcn_exp2f)
  return __builtin_amdgcn_exp2f(x);  // raw v_exp_f32, no denorm guard
#else
  return exp2f(x);
#endif
}

// ---------------- LayerNorm + cast to bf16 ----------------
__global__ __launch_bounds__(256) void ln_kernel(
    const float* __restrict__ x, const float* __restrict__ gamma,
    const float* __restrict__ beta, __bf16* __restrict__ xnb) {
  const int row = blockIdx.x;
  const int tid = threadIdx.x;
  const float4* xr = (const float4*)(x + (size_t)row * DIM);
  float4 v = xr[tid];
  float s1 = v.x + v.y + v.z + v.w;
  float s2 = v.x * v.x + v.y * v.y + v.z * v.z + v.w * v.w;
#pragma unroll
  for (int d = 32; d > 0; d >>= 1) {
    s1 += __shfl_xor(s1, d);
    s2 += __shfl_xor(s2, d);
  }
  __shared__ float red1[4], red2[4];
  const int wave = tid >> 6, lane = tid & 63;
  if (lane == 0) { red1[wave] = s1; red2[wave] = s2; }
  __syncthreads();
  s1 = red1[0] + red1[1] + red1[2] + red1[3];
  s2 = red2[0] + red2[1] + red2[2] + red2[3];
  const float mean = s1 * (1.0f / DIM);
  const float var = s2 * (1.0f / DIM) - mean * mean;
  const float rstd = rsqrtf(var + 1e-5f);
  float4 g = ((const float4*)gamma)[tid];
  float4 b = ((const float4*)beta)[tid];
  bf16x4 o;
  o[0] = (__bf16)((v.x - mean) * rstd * g.x + b.x);
  o[1] = (__bf16)((v.y - mean) * rstd * g.y + b.y);
  o[2] = (__bf16)((v.z - mean) * rstd * g.z + b.z);
  o[3] = (__bf16)((v.w - mean) * rstd * g.w + b.w);
  *(bf16x4*)(xnb + (size_t)row * DIM + tid * 4) = o;
}

// ---------------- transpose + cast (K x N fp32 -> N x K bf16) ----------------
__global__ __launch_bounds__(256) void transpose_cast(
    const float* __restrict__ in, __bf16* __restrict__ outT, int rows, int cols) {
  __shared__ float tile[32][33];
  const int tx = threadIdx.x & 31, ty = threadIdx.x >> 5;  // ty 0..7
  const int c0 = blockIdx.x * 32, r0 = blockIdx.y * 32;
#pragma unroll
  for (int rr = ty; rr < 32; rr += 8)
    tile[rr][tx] = in[(size_t)(r0 + rr) * cols + c0 + tx];
  __syncthreads();
#pragma unroll
  for (int rr = ty; rr < 32; rr += 8)
    outT[(size_t)(c0 + rr) * rows + r0 + tx] = (__bf16)tile[tx][rr];
}

// ---------------- 128x128 MFMA GEMM, A (MxK) @ Bt (NxK), both bf16 ----------------
// Orientation trick: for MODE 0 and Q/K we compute C^T (mfma(b,a)) so each lane owns
// 4 CONSECUTIVE output columns -> dwordx4 / b64 stores. For V we keep C (mfma(a,b))
// so each lane owns 4 consecutive seq for fixed dh -> direct b64 stores into
// (b,h,dh,seq); the old LDS V-transpose (+4 barriers) is gone.
template <int MODE>
__global__ __launch_bounds__(256) void gemm128(
    const __bf16* __restrict__ A, const __bf16* __restrict__ Bt, int K, int N,
    float* __restrict__ Cout, __bf16* __restrict__ qb, __bf16* __restrict__ kb,
    __bf16* __restrict__ vtb) {
  __shared__ __bf16 As[128 * 32];
  __shared__ __bf16 Bs[128 * 32];
  const int tid = threadIdx.x;
  const int wave = tid >> 6, lane = tid & 63;
  const int quad = lane >> 4, l16 = lane & 15;
  const int wm = wave >> 1, wn = wave & 1;
  const size_t tileM = (size_t)blockIdx.x * 128;
  const size_t tileN = (size_t)blockIdx.y * 128;
  const int sel = (MODE == 1) ? (int)(tileN >> 10) : 0;  // 0=q 1=k 2=v
  const bool vmode = (MODE == 1) && (sel == 2);

  f32x4 acc[4][4];
#pragma unroll
  for (int i = 0; i < 4; ++i)
#pragma unroll
    for (int j = 0; j < 4; ++j) acc[i][j] = (f32x4){0.f, 0.f, 0.f, 0.f};

  const int sr = lane >> 2;       // 0..15 row within 16-row group
  const int sc = lane & 3;        // chunk 0..3
  const int ck = (l16 >> 1) & 3;  // read-side swizzle key

  for (int k0 = 0; k0 < K; k0 += 32) {
    __syncthreads();
#pragma unroll
    for (int p = 0; p < 2; ++p) {
      const int rbase = p * 64 + wave * 16;
      const int row = rbase + sr;
      const int gc = (sc ^ ((row >> 1) & 3)) << 3;
      gload16(A + (tileM + row) * (size_t)K + k0 + gc, &As[rbase * 32]);
      gload16(Bt + (tileN + row) * (size_t)K + k0 + gc, &Bs[rbase * 32]);
    }
    __syncthreads();
    bf16x8 af[4], bfr[4];
#pragma unroll
    for (int mt = 0; mt < 4; ++mt)
      af[mt] = *(const bf16x8*)&As[(wm * 64 + mt * 16 + l16) * 32 + ((quad ^ ck) << 3)];
#pragma unroll
    for (int nt = 0; nt < 4; ++nt)
      bfr[nt] = *(const bf16x8*)&Bs[(wn * 64 + nt * 16 + l16) * 32 + ((quad ^ ck) << 3)];
    if (vmode) {
#pragma unroll
      for (int mt = 0; mt < 4; ++mt)
#pragma unroll
        for (int nt = 0; nt < 4; ++nt)
          acc[mt][nt] = __builtin_amdgcn_mfma_f32_16x16x32_bf16(af[mt], bfr[nt],
                                                                acc[mt][nt], 0, 0, 0);
    } else {
#pragma unroll
      for (int mt = 0; mt < 4; ++mt)
#pragma unroll
        for (int nt = 0; nt < 4; ++nt)
          acc[mt][nt] = __builtin_amdgcn_mfma_f32_16x16x32_bf16(bfr[nt], af[mt],
                                                                acc[mt][nt], 0, 0, 0);
    }
  }

  if (MODE == 0) {
    // C^T layout: col=l16 -> m-row; reg r -> consecutive n-cols
#pragma unroll
    for (int mt = 0; mt < 4; ++mt) {
      const size_t m = tileM + wm * 64 + mt * 16 + l16;
#pragma unroll
      for (int nt = 0; nt < 4; ++nt) {
        const size_t n0 = tileN + wn * 64 + nt * 16 + quad * 4;
        *(f32x4*)&Cout[m * (size_t)N + n0] = acc[mt][nt];
      }
    }
  } else if (sel < 2) {
    __bf16* dst = (sel == 0) ? qb : kb;
#pragma unroll
    for (int mt = 0; mt < 4; ++mt) {
      const size_t m = tileM + wm * 64 + mt * 16 + l16;
      const int b = (int)(m >> 11), seq = (int)(m & 2047);
#pragma unroll
      for (int nt = 0; nt < 4; ++nt) {
        const int c = (int)(tileN & 1023) + wn * 64 + nt * 16 + quad * 4;
        const int head = c >> 6, dh = c & 63;
        bf16x4 pk;
#pragma unroll
        for (int r = 0; r < 4; ++r) pk[r] = (__bf16)acc[mt][nt][r];
        *(bf16x4*)&dst[(((size_t)b * HEADS + head) * SEQ + seq) * DH + dh] = pk;
      }
    }
  } else {
    // V, normal C layout: col=l16 -> dh; reg r -> consecutive seq
#pragma unroll
    for (int nt = 0; nt < 4; ++nt) {
      const int c = (int)(tileN & 1023) + wn * 64 + nt * 16 + l16;
      const int head = c >> 6, dh = c & 63;
#pragma unroll
      for (int mt = 0; mt < 4; ++mt) {
        const size_t m0 = tileM + wm * 64 + mt * 16 + quad * 4;
        const int b = (int)(m0 >> 11), seq = (int)(m0 & 2047);
        bf16x4 pk;
#pragma unroll
        for (int r = 0; r < 4; ++r) pk[r] = (__bf16)acc[mt][nt][r];
        *(bf16x4*)&vtb[(((size_t)b * HEADS + head) * DH + dh) * SEQ + seq] = pk;
      }
    }
  }
}

// ---------------- flash-style causal attention (S^T formulation) ----------------
// grid: (BATCH*HEADS, 8): x = bh so all 8 blocks of a head land on ONE XCD
// (round-robin dispatch: XCD = linear_id % 8 = bh % 8) -> K/V served from that
// XCD's L2 (8 heads x 512 KB = 4 MB working set = L2 size).
// Block y handles q-tiles y and 15-y -> exactly 17 kv-iters (perfect balance).
__global__ __launch_bounds__(256) void attn_kernel(
    const __bf16* __restrict__ qb, const __bf16* __restrict__ kb,
    const __bf16* __restrict__ vtb, __bf16* __restrict__ ob) {
  const int bh = blockIdx.x;
  const int bx = blockIdx.y;  // 0..7
  const int tid = threadIdx.x;
  const int wave = tid >> 6, lane = tid & 63;
  const int quad = lane >> 4, l16 = lane & 15;

  __shared__ __bf16 Ks[2][128 * 64];
  __shared__ __bf16 Vs[2][64 * 128];
  __shared__ __bf16 Ps[4][32 * 36];  // per-wave P^T chunk: 32 qrows x 32 kv (+pad)

  const __bf16* kg = kb + (size_t)bh * SEQ * DH;
  const __bf16* vg = vtb + (size_t)bh * DH * SEQ;

  const int i1 = bx, i2 = 15 - bx;
  const int T = 17;

  const int kr = lane >> 3, kc = lane & 7;   // K stage: 8 rows x 8 chunks
  const int vr = lane >> 4, vc = lane & 15;  // V stage: 4 rows x 16 chunks

  auto stage = [&](int buf, int j) {
#pragma unroll
    for (int p = 0; p < 4; ++p) {
      const int rbase = p * 32 + wave * 8;
      const int row = rbase + kr;
      gload16(kg + (size_t)(j * 128 + row) * DH + ((kc ^ (row & 7)) << 3),
              &Ks[buf][rbase * 64]);
    }
#pragma unroll
    for (int p = 0; p < 4; ++p) {
      const int rbase = p * 16 + wave * 4;
      const int row = rbase + vr;
      gload16(vg + (size_t)row * SEQ + j * 128 + ((vc ^ (row & 7)) << 3),
              &Vs[buf][rbase * 128]);
    }
  };

  // Q as B-operand fragments, pre-scaled by dh^-0.5 * log2(e) (exp2 domain)
  const float QSCALE = 0.125f * 1.44269504088896f;
  bf16x8 qf[2][2];
  auto load_q = [&](int i) {
    const __bf16* qbase = qb + ((size_t)bh * SEQ + (size_t)i * 128 + wave * 32) * DH;
#pragma unroll
    for (int mt = 0; mt < 2; ++mt)
#pragma unroll
      for (int ks = 0; ks < 2; ++ks) {
        bf16x8 v = *(const bf16x8*)(qbase + (mt * 16 + l16) * DH + ks * 32 + quad * 8);
#pragma unroll
        for (int e = 0; e < 8; ++e) v[e] = (__bf16)((float)v[e] * QSCALE);
        qf[mt][ks] = v;
      }
  };

  float m_i[2], l_i[2];      // m: row-global; l: LANE-PARTIAL (reduced at epilogue)
  f32x4 o_acc[4][2];         // O^T: [md dh-frag][mt q-frag], col=l16=qrow
  auto reset_state = [&]() {
#pragma unroll
    for (int mt = 0; mt < 2; ++mt) { m_i[mt] = -1e30f; l_i[mt] = 0.f; }
#pragma unroll
    for (int md = 0; md < 4; ++md)
#pragma unroll
      for (int mt = 0; mt < 2; ++mt) o_acc[md][mt] = (f32x4){0.f, 0.f, 0.f, 0.f};
  };
  const int b_out = bh >> 4, h_out = bh & 15;
  auto epilogue = [&](int i) {
#pragma unroll
    for (int mt = 0; mt < 2; ++mt) {
      float lsum = l_i[mt];  // cross-quad all-reduce (deferred from the k-loop)
      lsum += __shfl_xor(lsum, 16);
      lsum += __shfl_xor(lsum, 32);
      const float inv = __builtin_amdgcn_rcpf(lsum);
      const int seq = i * 128 + wave * 32 + mt * 16 + l16;
      __bf16* dst = ob + ((size_t)b_out * SEQ + seq) * DIM + h_out * DH;
#pragma unroll
      for (int md = 0; md < 4; ++md) {
        bf16x4 pk;
#pragma unroll
        for (int r = 0; r < 4; ++r) pk[r] = (__bf16)(o_acc[md][mt][r] * inv);
        *(bf16x4*)(dst + md * 16 + quad * 4) = pk;
      }
    }
  };

  load_q(i1);
  reset_state();
  stage(0, 0);

  for (int t = 0; t < T; ++t) {
    __syncthreads();  // staging for t complete; prev-iter reads of this buf done
    if (t + 1 < T) {
      const int jn = (t + 1 <= bx) ? (t + 1) : (t - bx);
      stage((t + 1) & 1, jn);
    }
    const int buf = t & 1;
    const int i = (t <= bx) ? i1 : i2;
    const int j = (t <= bx) ? t : (t - bx - 1);
    const bool diag = (j == i);

    // S^T = K Q^T : rows(quad*4+r)=kv, cols(l16)=q-row
    f32x4 sa[8][2];
#pragma unroll
    for (int nt = 0; nt < 8; ++nt)
#pragma unroll
      for (int mt = 0; mt < 2; ++mt) sa[nt][mt] = (f32x4){0.f, 0.f, 0.f, 0.f};
#pragma unroll
    for (int nt = 0; nt < 8; ++nt)
#pragma unroll
      for (int ks = 0; ks < 2; ++ks) {
        bf16x8 kf = *(const bf16x8*)&Ks[buf][(nt * 16 + l16) * 64 +
                                            (((ks * 4 + quad) ^ (l16 & 7)) << 3)];
#pragma unroll
        for (int mt = 0; mt < 2; ++mt)
          sa[nt][mt] =
              __builtin_amdgcn_mfma_f32_16x16x32_bf16(kf, qf[mt][ks], sa[nt][mt], 0, 0, 0);
      }

    if (diag) {
#pragma unroll
      for (int nt = 0; nt < 8; ++nt)
#pragma unroll
        for (int mt = 0; mt < 2; ++mt) {
          const int qrow = wave * 32 + mt * 16 + l16;
#pragma unroll
          for (int r = 0; r < 4; ++r) {
            const int kv = nt * 16 + quad * 4 + r;
            if (kv > qrow) sa[nt][mt][r] = -1e30f;
          }
        }
    }

    // online softmax: lane owns 2 rows x 32 kv; only MAX needs cross-quad reduce
    float alpha[2];
#pragma unroll
    for (int mt = 0; mt < 2; ++mt) {
      float mx = -1e30f;
#pragma unroll
      for (int nt = 0; nt < 8; ++nt)
#pragma unroll
        for (int r = 0; r < 4; ++r) mx = fmaxf(mx, sa[nt][mt][r]);
      mx = fmaxf(mx, __shfl_xor(mx, 16));
      mx = fmaxf(mx, __shfl_xor(mx, 32));
      const float mnew = fmaxf(m_i[mt], mx);
      alpha[mt] = fast_exp2(m_i[mt] - mnew);
      m_i[mt] = mnew;
      float rs = 0.f;
#pragma unroll
      for (int nt = 0; nt < 8; ++nt)
#pragma unroll
        for (int r = 0; r < 4; ++r) {
          const float p = fast_exp2(sa[nt][mt][r] - mnew);
          sa[nt][mt][r] = p;
          rs += p;
        }
      l_i[mt] = l_i[mt] * alpha[mt] + rs;  // lane-partial sum; reduced at epilogue
    }
#pragma unroll
    for (int md = 0; md < 4; ++md)
#pragma unroll
      for (int mt = 0; mt < 2; ++mt)
#pragma unroll
        for (int r = 0; r < 4; ++r) o_acc[md][mt][r] *= alpha[mt];

    // O^T += V^T P^T in 4 chunks of 32 kv; Ps wave-private (no barrier)
#pragma unroll
    for (int c = 0; c < 4; ++c) {
#pragma unroll
      for (int mt = 0; mt < 2; ++mt)
#pragma unroll
        for (int ntl = 0; ntl < 2; ++ntl) {
          const int nt = c * 2 + ntl;
          bf16x4 pk;
#pragma unroll
          for (int r = 0; r < 4; ++r) pk[r] = (__bf16)sa[nt][mt][r];
          *(bf16x4*)&Ps[wave][(mt * 16 + l16) * 36 + ntl * 16 + quad * 4] = pk;
        }
      bf16x8 pf[2];
#pragma unroll
      for (int mt = 0; mt < 2; ++mt)
        pf[mt] = *(const bf16x8*)&Ps[wave][(mt * 16 + l16) * 36 + quad * 8];
#pragma unroll
      for (int md = 0; md < 4; ++md) {
        bf16x8 vf = *(const bf16x8*)&Vs[buf][(md * 16 + l16) * 128 +
                                            (((c * 4 + quad) ^ (l16 & 7)) << 3)];
#pragma unroll
        for (int mt = 0; mt < 2; ++mt)
          o_acc[md][mt] =
              __builtin_amdgcn_mfma_f32_16x16x32_bf16(vf, pf[mt], o_acc[md][mt], 0, 0, 0);
      }
    }

    if (t == bx) {  // phase 0 done: flush, switch to q-tile i2
      epilogue(i1);
      reset_state();
      load_q(i2);
    }
  }
  epilogue(i2);
}

// ---------------- launch ----------------
extern "C" void kernel_launch(void* const* d_in, const int* in_sizes, int n_in,
                              void* d_out, int out_size, void* d_ws, size_t ws_size,
                              hipStream_t stream) {
  const float* x = (const float*)d_in[0];
  const float* gamma = (const float*)d_in[1];
  const float* beta = (const float*)d_in[2];
  const float* w_qkv = (const float*)d_in[3];
  const float* w_out = (const float*)d_in[4];
  float* out = (float*)d_out;

  char* ws = (char*)d_ws;
  const size_t MB = 1024 * 1024;
  __bf16* xnb = (__bf16*)ws;                    // 16 MiB (dead after QKV gemm)
  __bf16* wqkvT = (__bf16*)(ws + 16 * MB);      // 6 MiB
  __bf16* woutT = (__bf16*)(ws + 24 * MB);      // 2 MiB
  __bf16* qbuf = (__bf16*)(ws + 32 * MB);       // 16 MiB
  __bf16* kbuf = (__bf16*)(ws + 48 * MB);       // 16 MiB
  __bf16* vtbuf = (__bf16*)(ws + 64 * MB);      // 16 MiB
  __bf16* attnb = xnb;                          // alias: xn dead by then

  ln_kernel<<<ROWS, 256, 0, stream>>>(x, gamma, beta, xnb);
  transpose_cast<<<dim3(NQKV / 32, DIM / 32), 256, 0, stream>>>(w_qkv, wqkvT, DIM, NQKV);
  transpose_cast<<<dim3(DIM / 32, DIM / 32), 256, 0, stream>>>(w_out, woutT, DIM, DIM);
  gemm128<1><<<dim3(ROWS / 128, NQKV / 128), 256, 0, stream>>>(
      xnb, wqkvT, DIM, NQKV, nullptr, qbuf, kbuf, vtbuf);
  attn_kernel<<<dim3(BATCH * HEADS, 8), 256, 0, stream>>>(qbuf, kbuf, vtbuf, attnb);
  gemm128<0><<<dim3(ROWS / 128, DIM / 128), 256, 0, stream>>>(
      attnb, woutT, DIM, DIM, out, nullptr, nullptr, nullptr);
}

// Round 6
// 316.243 us; speedup vs baseline: 1.0163x; 1.0163x over previous
//
#include <hip/hip_runtime.h>
#include <hip/hip_bf16.h>

#define DIM 1024
#define HEADS 16
#define DH 64
#define SEQ 2048
#define BATCH 4
#define ROWS (BATCH * SEQ)   // 8192
#define NQKV (3 * DIM)       // 3072

typedef __attribute__((ext_vector_type(8))) __bf16 bf16x8;
typedef __attribute__((ext_vector_type(4))) __bf16 bf16x4;
typedef __attribute__((ext_vector_type(4))) float f32x4;

__device__ inline void gload16(const void* g, void* l) {
  __builtin_amdgcn_global_load_lds(
      (const __attribute__((address_space(1))) void*)g,
      (__attribute__((address_space(3))) void*)l, 16, 0, 0);
}

__device__ inline float fast_exp2(float x) {
#if __has_builtin(__builtin_amdgcn_exp2f)
  return __builtin_amdgcn_exp2f(x);  // raw v_exp_f32, no denorm guard
#else
  return exp2f(x);
#endif
}

// ---------------- LayerNorm + cast to bf16 ----------------
__global__ __launch_bounds__(256) void ln_kernel(
    const float* __restrict__ x, const float* __restrict__ gamma,
    const float* __restrict__ beta, __bf16* __restrict__ xnb) {
  const int row = blockIdx.x;
  const int tid = threadIdx.x;
  const float4* xr = (const float4*)(x + (size_t)row * DIM);
  float4 v = xr[tid];
  float s1 = v.x + v.y + v.z + v.w;
  float s2 = v.x * v.x + v.y * v.y + v.z * v.z + v.w * v.w;
#pragma unroll
  for (int d = 32; d > 0; d >>= 1) {
    s1 += __shfl_xor(s1, d);
    s2 += __shfl_xor(s2, d);
  }
  __shared__ float red1[4], red2[4];
  const int wave = tid >> 6, lane = tid & 63;
  if (lane == 0) { red1[wave] = s1; red2[wave] = s2; }
  __syncthreads();
  s1 = red1[0] + red1[1] + red1[2] + red1[3];
  s2 = red2[0] + red2[1] + red2[2] + red2[3];
  const float mean = s1 * (1.0f / DIM);
  const float var = s2 * (1.0f / DIM) - mean * mean;
  const float rstd = rsqrtf(var + 1e-5f);
  float4 g = ((const float4*)gamma)[tid];
  float4 b = ((const float4*)beta)[tid];
  bf16x4 o;
  o[0] = (__bf16)((v.x - mean) * rstd * g.x + b.x);
  o[1] = (__bf16)((v.y - mean) * rstd * g.y + b.y);
  o[2] = (__bf16)((v.z - mean) * rstd * g.z + b.z);
  o[3] = (__bf16)((v.w - mean) * rstd * g.w + b.w);
  *(bf16x4*)(xnb + (size_t)row * DIM + tid * 4) = o;
}

// ---------------- transpose + cast (K x N fp32 -> N x K bf16) ----------------
__global__ __launch_bounds__(256) void transpose_cast(
    const float* __restrict__ in, __bf16* __restrict__ outT, int rows, int cols) {
  __shared__ float tile[32][33];
  const int tx = threadIdx.x & 31, ty = threadIdx.x >> 5;  // ty 0..7
  const int c0 = blockIdx.x * 32, r0 = blockIdx.y * 32;
#pragma unroll
  for (int rr = ty; rr < 32; rr += 8)
    tile[rr][tx] = in[(size_t)(r0 + rr) * cols + c0 + tx];
  __syncthreads();
#pragma unroll
  for (int rr = ty; rr < 32; rr += 8)
    outT[(size_t)(c0 + rr) * rows + r0 + tx] = (__bf16)tile[tx][rr];
}

// ---------------- 128x128 MFMA GEMM, A (MxK) @ Bt (NxK), both bf16 ----------------
// K-loop: double-buffered LDS; stage(k+1) issued AFTER the barrier and BEFORE
// compute(k) so the DMA overlaps the 16 MFMAs + ds_reads (attn-kernel structure;
// the old 2-barrier shape drained vmcnt(0) right after issuing -> naked latency).
// Orientation trick: MODE 0 and Q/K compute C^T (mfma(b,a)) -> lane owns 4
// consecutive columns -> dwordx4/b64 stores. V keeps C -> b64 into (b,h,dh,seq).
template <int MODE>
__global__ __launch_bounds__(256) void gemm128(
    const __bf16* __restrict__ A, const __bf16* __restrict__ Bt, int K, int N,
    float* __restrict__ Cout, __bf16* __restrict__ qb, __bf16* __restrict__ kb,
    __bf16* __restrict__ vtb) {
  __shared__ __bf16 As[2][128 * 32];
  __shared__ __bf16 Bs[2][128 * 32];
  const int tid = threadIdx.x;
  const int wave = tid >> 6, lane = tid & 63;
  const int quad = lane >> 4, l16 = lane & 15;
  const int wm = wave >> 1, wn = wave & 1;
  const size_t tileM = (size_t)blockIdx.x * 128;
  const size_t tileN = (size_t)blockIdx.y * 128;
  const int sel = (MODE == 1) ? (int)(tileN >> 10) : 0;  // 0=q 1=k 2=v
  const bool vmode = (MODE == 1) && (sel == 2);

  f32x4 acc[4][4];
#pragma unroll
  for (int i = 0; i < 4; ++i)
#pragma unroll
    for (int j = 0; j < 4; ++j) acc[i][j] = (f32x4){0.f, 0.f, 0.f, 0.f};

  const int sr = lane >> 2;       // 0..15 row within 16-row group
  const int sc = lane & 3;        // chunk 0..3
  const int ck = (l16 >> 1) & 3;  // read-side swizzle key

  const __bf16* Abase = A + tileM * (size_t)K;
  const __bf16* Bbase = Bt + tileN * (size_t)K;

  auto stage = [&](int buf, int k0) {
#pragma unroll
    for (int p = 0; p < 2; ++p) {
      const int rbase = p * 64 + wave * 16;
      const int row = rbase + sr;
      const int gc = (sc ^ ((row >> 1) & 3)) << 3;
      gload16(Abase + (size_t)row * K + k0 + gc, &As[buf][rbase * 32]);
      gload16(Bbase + (size_t)row * K + k0 + gc, &Bs[buf][rbase * 32]);
    }
  };

  const int NIT = K >> 5;
  stage(0, 0);
  for (int it = 0; it < NIT; ++it) {
    __syncthreads();  // stage(it) complete; buf (it+1)&1 fully consumed
    if (it + 1 < NIT) stage((it + 1) & 1, (it + 1) << 5);  // overlaps compute(it)
    const int buf = it & 1;
    bf16x8 af[4], bfr[4];
#pragma unroll
    for (int mt = 0; mt < 4; ++mt)
      af[mt] =
          *(const bf16x8*)&As[buf][(wm * 64 + mt * 16 + l16) * 32 + ((quad ^ ck) << 3)];
#pragma unroll
    for (int nt = 0; nt < 4; ++nt)
      bfr[nt] =
          *(const bf16x8*)&Bs[buf][(wn * 64 + nt * 16 + l16) * 32 + ((quad ^ ck) << 3)];
    if (vmode) {
#pragma unroll
      for (int mt = 0; mt < 4; ++mt)
#pragma unroll
        for (int nt = 0; nt < 4; ++nt)
          acc[mt][nt] = __builtin_amdgcn_mfma_f32_16x16x32_bf16(af[mt], bfr[nt],
                                                                acc[mt][nt], 0, 0, 0);
    } else {
#pragma unroll
      for (int mt = 0; mt < 4; ++mt)
#pragma unroll
        for (int nt = 0; nt < 4; ++nt)
          acc[mt][nt] = __builtin_amdgcn_mfma_f32_16x16x32_bf16(bfr[nt], af[mt],
                                                                acc[mt][nt], 0, 0, 0);
    }
  }

  if (MODE == 0) {
    // C^T layout: col=l16 -> m-row; reg r -> consecutive n-cols
#pragma unroll
    for (int mt = 0; mt < 4; ++mt) {
      const size_t m = tileM + wm * 64 + mt * 16 + l16;
#pragma unroll
      for (int nt = 0; nt < 4; ++nt) {
        const size_t n0 = tileN + wn * 64 + nt * 16 + quad * 4;
        *(f32x4*)&Cout[m * (size_t)N + n0] = acc[mt][nt];
      }
    }
  } else if (sel < 2) {
    __bf16* dst = (sel == 0) ? qb : kb;
#pragma unroll
    for (int mt = 0; mt < 4; ++mt) {
      const size_t m = tileM + wm * 64 + mt * 16 + l16;
      const int b = (int)(m >> 11), seq = (int)(m & 2047);
#pragma unroll
      for (int nt = 0; nt < 4; ++nt) {
        const int c = (int)(tileN & 1023) + wn * 64 + nt * 16 + quad * 4;
        const int head = c >> 6, dh = c & 63;
        bf16x4 pk;
#pragma unroll
        for (int r = 0; r < 4; ++r) pk[r] = (__bf16)acc[mt][nt][r];
        *(bf16x4*)&dst[(((size_t)b * HEADS + head) * SEQ + seq) * DH + dh] = pk;
      }
    }
  } else {
    // V, normal C layout: col=l16 -> dh; reg r -> consecutive seq
#pragma unroll
    for (int nt = 0; nt < 4; ++nt) {
      const int c = (int)(tileN & 1023) + wn * 64 + nt * 16 + l16;
      const int head = c >> 6, dh = c & 63;
#pragma unroll
      for (int mt = 0; mt < 4; ++mt) {
        const size_t m0 = tileM + wm * 64 + mt * 16 + quad * 4;
        const int b = (int)(m0 >> 11), seq = (int)(m0 & 2047);
        bf16x4 pk;
#pragma unroll
        for (int r = 0; r < 4; ++r) pk[r] = (__bf16)acc[mt][nt][r];
        *(bf16x4*)&vtb[(((size_t)b * HEADS + head) * DH + dh) * SEQ + seq] = pk;
      }
    }
  }
}

// ---------------- flash-style causal attention (S^T formulation) ----------------
// grid: (BATCH*HEADS, 8): x = bh so all 8 blocks of a head land on ONE XCD
// (round-robin dispatch: XCD = linear_id % 8 = bh % 8) -> K/V served from that
// XCD's L2. Block y handles q-tiles y and 15-y -> exactly 17 kv-iters.
__global__ __launch_bounds__(256) void attn_kernel(
    const __bf16* __restrict__ qb, const __bf16* __restrict__ kb,
    const __bf16* __restrict__ vtb, __bf16* __restrict__ ob) {
  const int bh = blockIdx.x;
  const int bx = blockIdx.y;  // 0..7
  const int tid = threadIdx.x;
  const int wave = tid >> 6, lane = tid & 63;
  const int quad = lane >> 4, l16 = lane & 15;

  __shared__ __bf16 Ks[2][128 * 64];
  __shared__ __bf16 Vs[2][64 * 128];
  __shared__ __bf16 Ps[4][32 * 36];  // per-wave P^T chunk: 32 qrows x 32 kv (+pad)

  const __bf16* kg = kb + (size_t)bh * SEQ * DH;
  const __bf16* vg = vtb + (size_t)bh * DH * SEQ;

  const int i1 = bx, i2 = 15 - bx;
  const int T = 17;

  const int kr = lane >> 3, kc = lane & 7;   // K stage: 8 rows x 8 chunks
  const int vr = lane >> 4, vc = lane & 15;  // V stage: 4 rows x 16 chunks

  auto stage = [&](int buf, int j) {
#pragma unroll
    for (int p = 0; p < 4; ++p) {
      const int rbase = p * 32 + wave * 8;
      const int row = rbase + kr;
      gload16(kg + (size_t)(j * 128 + row) * DH + ((kc ^ (row & 7)) << 3),
              &Ks[buf][rbase * 64]);
    }
#pragma unroll
    for (int p = 0; p < 4; ++p) {
      const int rbase = p * 16 + wave * 4;
      const int row = rbase + vr;
      gload16(vg + (size_t)row * SEQ + j * 128 + ((vc ^ (row & 7)) << 3),
              &Vs[buf][rbase * 128]);
    }
  };

  // Q as B-operand fragments, pre-scaled by dh^-0.5 * log2(e) (exp2 domain)
  const float QSCALE = 0.125f * 1.44269504088896f;
  bf16x8 qf[2][2];
  auto load_q = [&](int i) {
    const __bf16* qbase = qb + ((size_t)bh * SEQ + (size_t)i * 128 + wave * 32) * DH;
#pragma unroll
    for (int mt = 0; mt < 2; ++mt)
#pragma unroll
      for (int ks = 0; ks < 2; ++ks) {
        bf16x8 v = *(const bf16x8*)(qbase + (mt * 16 + l16) * DH + ks * 32 + quad * 8);
#pragma unroll
        for (int e = 0; e < 8; ++e) v[e] = (__bf16)((float)v[e] * QSCALE);
        qf[mt][ks] = v;
      }
  };

  float m_i[2], l_i[2];      // m: row-global; l: LANE-PARTIAL (reduced at epilogue)
  f32x4 o_acc[4][2];         // O^T: [md dh-frag][mt q-frag], col=l16=qrow
  auto reset_state = [&]() {
#pragma unroll
    for (int mt = 0; mt < 2; ++mt) { m_i[mt] = -1e30f; l_i[mt] = 0.f; }
#pragma unroll
    for (int md = 0; md < 4; ++md)
#pragma unroll
      for (int mt = 0; mt < 2; ++mt) o_acc[md][mt] = (f32x4){0.f, 0.f, 0.f, 0.f};
  };
  const int b_out = bh >> 4, h_out = bh & 15;
  auto epilogue = [&](int i) {
#pragma unroll
    for (int mt = 0; mt < 2; ++mt) {
      float lsum = l_i[mt];  // cross-quad all-reduce (deferred from the k-loop)
      lsum += __shfl_xor(lsum, 16);
      lsum += __shfl_xor(lsum, 32);
      const float inv = __builtin_amdgcn_rcpf(lsum);
      const int seq = i * 128 + wave * 32 + mt * 16 + l16;
      __bf16* dst = ob + ((size_t)b_out * SEQ + seq) * DIM + h_out * DH;
#pragma unroll
      for (int md = 0; md < 4; ++md) {
        bf16x4 pk;
#pragma unroll
        for (int r = 0; r < 4; ++r) pk[r] = (__bf16)(o_acc[md][mt][r] * inv);
        *(bf16x4*)(dst + md * 16 + quad * 4) = pk;
      }
    }
  };

  load_q(i1);
  reset_state();
  stage(0, 0);

  for (int t = 0; t < T; ++t) {
    __syncthreads();  // staging for t complete; prev-iter reads of this buf done
    if (t + 1 < T) {
      const int jn = (t + 1 <= bx) ? (t + 1) : (t - bx);
      stage((t + 1) & 1, jn);
    }
    const int buf = t & 1;
    const int i = (t <= bx) ? i1 : i2;
    const int j = (t <= bx) ? t : (t - bx - 1);
    const bool diag = (j == i);

    // S^T = K Q^T : rows(quad*4+r)=kv, cols(l16)=q-row
    f32x4 sa[8][2];
#pragma unroll
    for (int nt = 0; nt < 8; ++nt)
#pragma unroll
      for (int mt = 0; mt < 2; ++mt) sa[nt][mt] = (f32x4){0.f, 0.f, 0.f, 0.f};
#pragma unroll
    for (int nt = 0; nt < 8; ++nt)
#pragma unroll
      for (int ks = 0; ks < 2; ++ks) {
        bf16x8 kf = *(const bf16x8*)&Ks[buf][(nt * 16 + l16) * 64 +
                                            (((ks * 4 + quad) ^ (l16 & 7)) << 3)];
#pragma unroll
        for (int mt = 0; mt < 2; ++mt)
          sa[nt][mt] =
              __builtin_amdgcn_mfma_f32_16x16x32_bf16(kf, qf[mt][ks], sa[nt][mt], 0, 0, 0);
      }

    if (diag) {
#pragma unroll
      for (int nt = 0; nt < 8; ++nt)
#pragma unroll
        for (int mt = 0; mt < 2; ++mt) {
          const int qrow = wave * 32 + mt * 16 + l16;
#pragma unroll
          for (int r = 0; r < 4; ++r) {
            const int kv = nt * 16 + quad * 4 + r;
            if (kv > qrow) sa[nt][mt][r] = -1e30f;
          }
        }
    }

    // online softmax: lane owns 2 rows x 32 kv; only MAX needs cross-quad reduce
    float alpha[2];
#pragma unroll
    for (int mt = 0; mt < 2; ++mt) {
      float mx = -1e30f;
#pragma unroll
      for (int nt = 0; nt < 8; ++nt)
#pragma unroll
        for (int r = 0; r < 4; ++r) mx = fmaxf(mx, sa[nt][mt][r]);
      mx = fmaxf(mx, __shfl_xor(mx, 16));
      mx = fmaxf(mx, __shfl_xor(mx, 32));
      const float mnew = fmaxf(m_i[mt], mx);
      alpha[mt] = fast_exp2(m_i[mt] - mnew);
      m_i[mt] = mnew;
      float rs = 0.f;
#pragma unroll
      for (int nt = 0; nt < 8; ++nt)
#pragma unroll
        for (int r = 0; r < 4; ++r) {
          const float p = fast_exp2(sa[nt][mt][r] - mnew);
          sa[nt][mt][r] = p;
          rs += p;
        }
      l_i[mt] = l_i[mt] * alpha[mt] + rs;  // lane-partial sum; reduced at epilogue
    }
#pragma unroll
    for (int md = 0; md < 4; ++md)
#pragma unroll
      for (int mt = 0; mt < 2; ++mt)
#pragma unroll
        for (int r = 0; r < 4; ++r) o_acc[md][mt][r] *= alpha[mt];

    // O^T += V^T P^T in 4 chunks of 32 kv; Ps wave-private (no barrier)
#pragma unroll
    for (int c = 0; c < 4; ++c) {
#pragma unroll
      for (int mt = 0; mt < 2; ++mt)
#pragma unroll
        for (int ntl = 0; ntl < 2; ++ntl) {
          const int nt = c * 2 + ntl;
          bf16x4 pk;
#pragma unroll
          for (int r = 0; r < 4; ++r) pk[r] = (__bf16)sa[nt][mt][r];
          *(bf16x4*)&Ps[wave][(mt * 16 + l16) * 36 + ntl * 16 + quad * 4] = pk;
        }
      bf16x8 pf[2];
#pragma unroll
      for (int mt = 0; mt < 2; ++mt)
        pf[mt] = *(const bf16x8*)&Ps[wave][(mt * 16 + l16) * 36 + quad * 8];
#pragma unroll
      for (int md = 0; md < 4; ++md) {
        bf16x8 vf = *(const bf16x8*)&Vs[buf][(md * 16 + l16) * 128 +
                                            (((c * 4 + quad) ^ (l16 & 7)) << 3)];
#pragma unroll
        for (int mt = 0; mt < 2; ++mt)
          o_acc[md][mt] =
              __builtin_amdgcn_mfma_f32_16x16x32_bf16(vf, pf[mt], o_acc[md][mt], 0, 0, 0);
      }
    }

    if (t == bx) {  // phase 0 done: flush, switch to q-tile i2
      epilogue(i1);
      reset_state();
      load_q(i2);
    }
  }
  epilogue(i2);
}

// ---------------- launch ----------------
extern "C" void kernel_launch(void* const* d_in, const int* in_sizes, int n_in,
                              void* d_out, int out_size, void* d_ws, size_t ws_size,
                              hipStream_t stream) {
  const float* x = (const float*)d_in[0];
  const float* gamma = (const float*)d_in[1];
  const float* beta = (const float*)d_in[2];
  const float* w_qkv = (const float*)d_in[3];
  const float* w_out = (const float*)d_in[4];
  float* out = (float*)d_out;

  char* ws = (char*)d_ws;
  const size_t MB = 1024 * 1024;
  __bf16* xnb = (__bf16*)ws;                    // 16 MiB (dead after QKV gemm)
  __bf16* wqkvT = (__bf16*)(ws + 16 * MB);      // 6 MiB
  __bf16* woutT = (__bf16*)(ws + 24 * MB);      // 2 MiB
  __bf16* qbuf = (__bf16*)(ws + 32 * MB);       // 16 MiB
  __bf16* kbuf = (__bf16*)(ws + 48 * MB);       // 16 MiB
  __bf16* vtbuf = (__bf16*)(ws + 64 * MB);      // 16 MiB
  __bf16* attnb = xnb;                          // alias: xn dead by then

  ln_kernel<<<ROWS, 256, 0, stream>>>(x, gamma, beta, xnb);
  transpose_cast<<<dim3(NQKV / 32, DIM / 32), 256, 0, stream>>>(w_qkv, wqkvT, DIM, NQKV);
  transpose_cast<<<dim3(DIM / 32, DIM / 32), 256, 0, stream>>>(w_out, woutT, DIM, DIM);
  gemm128<1><<<dim3(ROWS / 128, NQKV / 128), 256, 0, stream>>>(
      xnb, wqkvT, DIM, NQKV, nullptr, qbuf, kbuf, vtbuf);
  attn_kernel<<<dim3(BATCH * HEADS, 8), 256, 0, stream>>>(qbuf, kbuf, vtbuf, attnb);
  gemm128<0><<<dim3(ROWS / 128, DIM / 128), 256, 0, stream>>>(
      attnb, woutT, DIM, DIM, out, nullptr, nullptr, nullptr);
}

// Round 7
// 287.033 us; speedup vs baseline: 1.1197x; 1.1018x over previous
//
#include <hip/hip_runtime.h>
#include <hip/hip_bf16.h>

#define DIM 1024
#define HEADS 16
#define DH 64
#define SEQ 2048
#define BATCH 4
#define ROWS (BATCH * SEQ)   // 8192
#define NQKV (3 * DIM)       // 3072

typedef __attribute__((ext_vector_type(8))) __bf16 bf16x8;
typedef __attribute__((ext_vector_type(4))) __bf16 bf16x4;
typedef __attribute__((ext_vector_type(4))) float f32x4;

__device__ inline void gload16(const void* g, void* l) {
  __builtin_amdgcn_global_load_lds(
      (const __attribute__((address_space(1))) void*)g,
      (__attribute__((address_space(3))) void*)l, 16, 0, 0);
}

__device__ inline float fast_exp2(float x) {
#if __has_builtin(__builtin_amdgcn_exp2f)
  return __builtin_amdgcn_exp2f(x);  // raw v_exp_f32, no denorm guard
#else
  return exp2f(x);
#endif
}

// ---------------- LayerNorm + cast to bf16 ----------------
__global__ __launch_bounds__(256) void ln_kernel(
    const float* __restrict__ x, const float* __restrict__ gamma,
    const float* __restrict__ beta, __bf16* __restrict__ xnb) {
  const int row = blockIdx.x;
  const int tid = threadIdx.x;
  const float4* xr = (const float4*)(x + (size_t)row * DIM);
  float4 v = xr[tid];
  float s1 = v.x + v.y + v.z + v.w;
  float s2 = v.x * v.x + v.y * v.y + v.z * v.z + v.w * v.w;
#pragma unroll
  for (int d = 32; d > 0; d >>= 1) {
    s1 += __shfl_xor(s1, d);
    s2 += __shfl_xor(s2, d);
  }
  __shared__ float red1[4], red2[4];
  const int wave = tid >> 6, lane = tid & 63;
  if (lane == 0) { red1[wave] = s1; red2[wave] = s2; }
  __syncthreads();
  s1 = red1[0] + red1[1] + red1[2] + red1[3];
  s2 = red2[0] + red2[1] + red2[2] + red2[3];
  const float mean = s1 * (1.0f / DIM);
  const float var = s2 * (1.0f / DIM) - mean * mean;
  const float rstd = rsqrtf(var + 1e-5f);
  float4 g = ((const float4*)gamma)[tid];
  float4 b = ((const float4*)beta)[tid];
  bf16x4 o;
  o[0] = (__bf16)((v.x - mean) * rstd * g.x + b.x);
  o[1] = (__bf16)((v.y - mean) * rstd * g.y + b.y);
  o[2] = (__bf16)((v.z - mean) * rstd * g.z + b.z);
  o[3] = (__bf16)((v.w - mean) * rstd * g.w + b.w);
  *(bf16x4*)(xnb + (size_t)row * DIM + tid * 4) = o;
}

// ---------------- transpose + cast (K x N fp32 -> N x K bf16) ----------------
__global__ __launch_bounds__(256) void transpose_cast(
    const float* __restrict__ in, __bf16* __restrict__ outT, int rows, int cols) {
  __shared__ float tile[32][33];
  const int tx = threadIdx.x & 31, ty = threadIdx.x >> 5;  // ty 0..7
  const int c0 = blockIdx.x * 32, r0 = blockIdx.y * 32;
#pragma unroll
  for (int rr = ty; rr < 32; rr += 8)
    tile[rr][tx] = in[(size_t)(r0 + rr) * cols + c0 + tx];
  __syncthreads();
#pragma unroll
  for (int rr = ty; rr < 32; rr += 8)
    outT[(size_t)(c0 + rr) * rows + r0 + tx] = (__bf16)tile[tx][rr];
}

// ---------------- 128x128 MFMA GEMM, A (MxK) @ Bt (NxK), both bf16 ----------------
// K-loop: double-buffered LDS; stage(k+1) after the barrier, before compute(k).
// Orientation: MODE 0 and Q/K compute C^T (mfma(b,a)) -> lane owns 4 consecutive
// columns -> dwordx4/b64 stores. V keeps C -> b64 into (b,h,dh,seq).
template <int MODE>
__global__ __launch_bounds__(256) void gemm128(
    const __bf16* __restrict__ A, const __bf16* __restrict__ Bt, int K, int N,
    float* __restrict__ Cout, __bf16* __restrict__ qb, __bf16* __restrict__ kb,
    __bf16* __restrict__ vtb) {
  __shared__ __bf16 As[2][128 * 32];
  __shared__ __bf16 Bs[2][128 * 32];
  const int tid = threadIdx.x;
  const int wave = tid >> 6, lane = tid & 63;
  const int quad = lane >> 4, l16 = lane & 15;
  const int wm = wave >> 1, wn = wave & 1;
  const size_t tileM = (size_t)blockIdx.x * 128;
  const size_t tileN = (size_t)blockIdx.y * 128;
  const int sel = (MODE == 1) ? (int)(tileN >> 10) : 0;  // 0=q 1=k 2=v
  const bool vmode = (MODE == 1) && (sel == 2);

  f32x4 acc[4][4];
#pragma unroll
  for (int i = 0; i < 4; ++i)
#pragma unroll
    for (int j = 0; j < 4; ++j) acc[i][j] = (f32x4){0.f, 0.f, 0.f, 0.f};

  const int sr = lane >> 2;       // 0..15 row within 16-row group
  const int sc = lane & 3;        // chunk 0..3
  const int ck = (l16 >> 1) & 3;  // read-side swizzle key

  const __bf16* Abase = A + tileM * (size_t)K;
  const __bf16* Bbase = Bt + tileN * (size_t)K;

  auto stage = [&](int buf, int k0) {
#pragma unroll
    for (int p = 0; p < 2; ++p) {
      const int rbase = p * 64 + wave * 16;
      const int row = rbase + sr;
      const int gc = (sc ^ ((row >> 1) & 3)) << 3;
      gload16(Abase + (size_t)row * K + k0 + gc, &As[buf][rbase * 32]);
      gload16(Bbase + (size_t)row * K + k0 + gc, &Bs[buf][rbase * 32]);
    }
  };

  const int NIT = K >> 5;
  stage(0, 0);
  for (int it = 0; it < NIT; ++it) {
    __syncthreads();  // stage(it) complete; buf (it+1)&1 fully consumed
    if (it + 1 < NIT) stage((it + 1) & 1, (it + 1) << 5);  // overlaps compute(it)
    const int buf = it & 1;
    bf16x8 af[4], bfr[4];
#pragma unroll
    for (int mt = 0; mt < 4; ++mt)
      af[mt] =
          *(const bf16x8*)&As[buf][(wm * 64 + mt * 16 + l16) * 32 + ((quad ^ ck) << 3)];
#pragma unroll
    for (int nt = 0; nt < 4; ++nt)
      bfr[nt] =
          *(const bf16x8*)&Bs[buf][(wn * 64 + nt * 16 + l16) * 32 + ((quad ^ ck) << 3)];
    if (vmode) {
#pragma unroll
      for (int mt = 0; mt < 4; ++mt)
#pragma unroll
        for (int nt = 0; nt < 4; ++nt)
          acc[mt][nt] = __builtin_amdgcn_mfma_f32_16x16x32_bf16(af[mt], bfr[nt],
                                                                acc[mt][nt], 0, 0, 0);
    } else {
#pragma unroll
      for (int mt = 0; mt < 4; ++mt)
#pragma unroll
        for (int nt = 0; nt < 4; ++nt)
          acc[mt][nt] = __builtin_amdgcn_mfma_f32_16x16x32_bf16(bfr[nt], af[mt],
                                                                acc[mt][nt], 0, 0, 0);
    }
  }

  if (MODE == 0) {
#pragma unroll
    for (int mt = 0; mt < 4; ++mt) {
      const size_t m = tileM + wm * 64 + mt * 16 + l16;
#pragma unroll
      for (int nt = 0; nt < 4; ++nt) {
        const size_t n0 = tileN + wn * 64 + nt * 16 + quad * 4;
        *(f32x4*)&Cout[m * (size_t)N + n0] = acc[mt][nt];
      }
    }
  } else if (sel < 2) {
    __bf16* dst = (sel == 0) ? qb : kb;
#pragma unroll
    for (int mt = 0; mt < 4; ++mt) {
      const size_t m = tileM + wm * 64 + mt * 16 + l16;
      const int b = (int)(m >> 11), seq = (int)(m & 2047);
#pragma unroll
      for (int nt = 0; nt < 4; ++nt) {
        const int c = (int)(tileN & 1023) + wn * 64 + nt * 16 + quad * 4;
        const int head = c >> 6, dh = c & 63;
        bf16x4 pk;
#pragma unroll
        for (int r = 0; r < 4; ++r) pk[r] = (__bf16)acc[mt][nt][r];
        *(bf16x4*)&dst[(((size_t)b * HEADS + head) * SEQ + seq) * DH + dh] = pk;
      }
    }
  } else {
#pragma unroll
    for (int nt = 0; nt < 4; ++nt) {
      const int c = (int)(tileN & 1023) + wn * 64 + nt * 16 + l16;
      const int head = c >> 6, dh = c & 63;
#pragma unroll
      for (int mt = 0; mt < 4; ++mt) {
        const size_t m0 = tileM + wm * 64 + mt * 16 + quad * 4;
        const int b = (int)(m0 >> 11), seq = (int)(m0 & 2047);
        bf16x4 pk;
#pragma unroll
        for (int r = 0; r < 4; ++r) pk[r] = (__bf16)acc[mt][nt][r];
        *(bf16x4*)&vtb[(((size_t)b * HEADS + head) * DH + dh) * SEQ + seq] = pk;
      }
    }
  }
}

// ---------------- flash-style causal attention, 64x64 tiles ----------------
// grid (BATCH*HEADS, 16): x = bh -> all 16 blocks of a head on ONE XCD
// (linear_id % 8 = bh % 8). Block y handles 64-row q-tiles y and 31-y:
// kv-iters = (y+1) + (31-y+1) = 33 for every block -> perfect balance.
// 1024 blocks = 4/CU; LDS 36.6 KB and __launch_bounds__(256,4) keep 4 resident
// -> 16 waves/CU (2x the 128-tile version). Wave owns 16 q-rows (mt=1):
// sa/o_acc/qf shrink 4x, softmax chain 4x shorter.
__global__ __launch_bounds__(256, 4) void attn_kernel(
    const __bf16* __restrict__ qb, const __bf16* __restrict__ kb,
    const __bf16* __restrict__ vtb, __bf16* __restrict__ ob) {
  const int bh = blockIdx.x;
  const int by = blockIdx.y;  // 0..15
  const int tid = threadIdx.x;
  const int wave = tid >> 6, lane = tid & 63;
  const int quad = lane >> 4, l16 = lane & 15;

  __shared__ __bf16 Ks[2][64 * 64];  // [kv][dh], 8 chunks/row, XOR-swizzled
  __shared__ __bf16 Vs[2][64 * 64];  // [dh][kv], 8 chunks/row, XOR-swizzled
  __shared__ __bf16 Ps[4][16 * 36];  // per-wave P^T chunk: 16 qrows x 32 kv (+pad)

  const __bf16* kg = kb + (size_t)bh * SEQ * DH;
  const __bf16* vg = vtb + (size_t)bh * DH * SEQ;

  const int i1 = by, i2 = 31 - by;
  const int T = 33;

  const int kr = lane >> 3, kc = lane & 7;  // stage: 8 rows x 8 chunks per instr

  auto stage = [&](int buf, int j) {
#pragma unroll
    for (int p = 0; p < 2; ++p) {
      const int rbase = wave * 16 + p * 8;
      const int row = rbase + kr;
      gload16(kg + (size_t)(j * 64 + row) * DH + ((kc ^ (row & 7)) << 3),
              &Ks[buf][rbase * 64]);
      gload16(vg + (size_t)row * SEQ + j * 64 + ((kc ^ (row & 7)) << 3),
              &Vs[buf][rbase * 64]);
    }
  };

  // Q as B-operand fragments, pre-scaled by dh^-0.5 * log2(e) (exp2 domain)
  const float QSCALE = 0.125f * 1.44269504088896f;
  bf16x8 qf[2];
  auto load_q = [&](int i) {
    const __bf16* qbase = qb + ((size_t)bh * SEQ + (size_t)i * 64 + wave * 16) * DH;
#pragma unroll
    for (int ks = 0; ks < 2; ++ks) {
      bf16x8 v = *(const bf16x8*)(qbase + l16 * DH + ks * 32 + quad * 8);
#pragma unroll
      for (int e = 0; e < 8; ++e) v[e] = (__bf16)((float)v[e] * QSCALE);
      qf[ks] = v;
    }
  };

  float m_i, l_i;     // one q-row per lane; l is LANE-PARTIAL (reduced at epilogue)
  f32x4 o_acc[4];     // O^T: [md dh-frag], col=l16=qrow
  auto reset_state = [&]() {
    m_i = -1e30f;
    l_i = 0.f;
#pragma unroll
    for (int md = 0; md < 4; ++md) o_acc[md] = (f32x4){0.f, 0.f, 0.f, 0.f};
  };
  const int b_out = bh >> 4, h_out = bh & 15;
  auto epilogue = [&](int i) {
    float lsum = l_i;  // cross-quad all-reduce (deferred from the k-loop)
    lsum += __shfl_xor(lsum, 16);
    lsum += __shfl_xor(lsum, 32);
    const float inv = __builtin_amdgcn_rcpf(lsum);
    const int seq = i * 64 + wave * 16 + l16;
    __bf16* dst = ob + ((size_t)b_out * SEQ + seq) * DIM + h_out * DH;
#pragma unroll
    for (int md = 0; md < 4; ++md) {
      bf16x4 pk;
#pragma unroll
      for (int r = 0; r < 4; ++r) pk[r] = (__bf16)(o_acc[md][r] * inv);
      *(bf16x4*)(dst + md * 16 + quad * 4) = pk;
    }
  };

  load_q(i1);
  reset_state();
  stage(0, 0);

  for (int t = 0; t < T; ++t) {
    __syncthreads();  // staging for t complete; prev reads of this buf done
    if (t + 1 < T) {
      const int jn = (t + 1 <= by) ? (t + 1) : (t - by);
      stage((t + 1) & 1, jn);
    }
    const int buf = t & 1;
    const int i = (t <= by) ? i1 : i2;
    const int j = (t <= by) ? t : (t - by - 1);
    const bool diag = (j == i);

    // S^T = K Q^T : rows(quad*4+r)=kv 0..63, cols(l16)=q-row (wave's 16 rows)
    f32x4 sa[4];
#pragma unroll
    for (int nt = 0; nt < 4; ++nt) sa[nt] = (f32x4){0.f, 0.f, 0.f, 0.f};
#pragma unroll
    for (int nt = 0; nt < 4; ++nt)
#pragma unroll
      for (int ks = 0; ks < 2; ++ks) {
        bf16x8 kf = *(const bf16x8*)&Ks[buf][(nt * 16 + l16) * 64 +
                                            (((ks * 4 + quad) ^ (l16 & 7)) << 3)];
        sa[nt] = __builtin_amdgcn_mfma_f32_16x16x32_bf16(kf, qf[ks], sa[nt], 0, 0, 0);
      }

    if (diag) {
      const int qrl = wave * 16 + l16;  // local q-row 0..63
#pragma unroll
      for (int nt = 0; nt < 4; ++nt)
#pragma unroll
        for (int r = 0; r < 4; ++r) {
          const int kvl = nt * 16 + quad * 4 + r;
          if (kvl > qrl) sa[nt][r] = -1e30f;
        }
    }

    // online softmax: lane owns 1 row x 16 kv; only MAX needs cross-quad reduce
    {
      float mx = -1e30f;
#pragma unroll
      for (int nt = 0; nt < 4; ++nt)
#pragma unroll
        for (int r = 0; r < 4; ++r) mx = fmaxf(mx, sa[nt][r]);
      mx = fmaxf(mx, __shfl_xor(mx, 16));
      mx = fmaxf(mx, __shfl_xor(mx, 32));
      const float mnew = fmaxf(m_i, mx);
      const float alpha = fast_exp2(m_i - mnew);
      m_i = mnew;
      float rs = 0.f;
#pragma unroll
      for (int nt = 0; nt < 4; ++nt)
#pragma unroll
        for (int r = 0; r < 4; ++r) {
          const float p = fast_exp2(sa[nt][r] - mnew);
          sa[nt][r] = p;
          rs += p;
        }
      l_i = l_i * alpha + rs;  // lane-partial; reduced at epilogue
#pragma unroll
      for (int md = 0; md < 4; ++md)
#pragma unroll
        for (int r = 0; r < 4; ++r) o_acc[md][r] *= alpha;
    }

    // O^T += V^T P^T in 2 chunks of 32 kv; Ps wave-private (no barrier)
#pragma unroll
    for (int c = 0; c < 2; ++c) {
#pragma unroll
      for (int ntl = 0; ntl < 2; ++ntl) {
        const int nt = c * 2 + ntl;
        bf16x4 pk;
#pragma unroll
        for (int r = 0; r < 4; ++r) pk[r] = (__bf16)sa[nt][r];
        *(bf16x4*)&Ps[wave][l16 * 36 + ntl * 16 + quad * 4] = pk;
      }
      bf16x8 pf = *(const bf16x8*)&Ps[wave][l16 * 36 + quad * 8];
#pragma unroll
      for (int md = 0; md < 4; ++md) {
        bf16x8 vf = *(const bf16x8*)&Vs[buf][(md * 16 + l16) * 64 +
                                            (((c * 4 + quad) ^ (l16 & 7)) << 3)];
        o_acc[md] = __builtin_amdgcn_mfma_f32_16x16x32_bf16(vf, pf, o_acc[md], 0, 0, 0);
      }
    }

    if (t == by) {  // phase 0 done: flush, switch to q-tile i2
      epilogue(i1);
      reset_state();
      load_q(i2);
    }
  }
  epilogue(i2);
}

// ---------------- launch ----------------
extern "C" void kernel_launch(void* const* d_in, const int* in_sizes, int n_in,
                              void* d_out, int out_size, void* d_ws, size_t ws_size,
                              hipStream_t stream) {
  const float* x = (const float*)d_in[0];
  const float* gamma = (const float*)d_in[1];
  const float* beta = (const float*)d_in[2];
  const float* w_qkv = (const float*)d_in[3];
  const float* w_out = (const float*)d_in[4];
  float* out = (float*)d_out;

  char* ws = (char*)d_ws;
  const size_t MB = 1024 * 1024;
  __bf16* xnb = (__bf16*)ws;                    // 16 MiB (dead after QKV gemm)
  __bf16* wqkvT = (__bf16*)(ws + 16 * MB);      // 6 MiB
  __bf16* woutT = (__bf16*)(ws + 24 * MB);      // 2 MiB
  __bf16* qbuf = (__bf16*)(ws + 32 * MB);       // 16 MiB
  __bf16* kbuf = (__bf16*)(ws + 48 * MB);       // 16 MiB
  __bf16* vtbuf = (__bf16*)(ws + 64 * MB);      // 16 MiB
  __bf16* attnb = xnb;                          // alias: xn dead by then

  ln_kernel<<<ROWS, 256, 0, stream>>>(x, gamma, beta, xnb);
  transpose_cast<<<dim3(NQKV / 32, DIM / 32), 256, 0, stream>>>(w_qkv, wqkvT, DIM, NQKV);
  transpose_cast<<<dim3(DIM / 32, DIM / 32), 256, 0, stream>>>(w_out, woutT, DIM, DIM);
  gemm128<1><<<dim3(ROWS / 128, NQKV / 128), 256, 0, stream>>>(
      xnb, wqkvT, DIM, NQKV, nullptr, qbuf, kbuf, vtbuf);
  attn_kernel<<<dim3(BATCH * HEADS, 16), 256, 0, stream>>>(qbuf, kbuf, vtbuf, attnb);
  gemm128<0><<<dim3(ROWS / 128, DIM / 128), 256, 0, stream>>>(
      attnb, woutT, DIM, DIM, out, nullptr, nullptr, nullptr);
}